// Round 1
// baseline (795.069 us; speedup 1.0000x reference)
//
#include <hip/hip_runtime.h>

#define ALPHA 0.1f
#define HDEPTH 8
#define STEPS 6            // H - 2
#define NCLASS 10000
#define NNODES 15000
#define BATCH 1024
#define NPAIRS (BATCH * STEPS)   // 6144

#define PACK_STRIDE 320    // u32 words per packed row (313 used, padded for 8B/64B align)
#define NCOLS 313          // ceil(NCLASS / 32)
#define NGROUPS 157        // ceil(NCLASS / 64) -- 64-class ballot groups
#define CHUNK 64           // pairs per main-kernel block (64 divides 1024 -> single s per chunk)
#define NCHUNKS (NPAIRS / CHUNK)  // 96

// ---------------------------------------------------------------------------
// Kernel A: build (n1, n2) node pairs (s-major: p = s*1024 + b) and flag every
// referenced node so the pack kernel only touches ~8.3k of 15k rows.
// ---------------------------------------------------------------------------
__global__ void build_pairs_kernel(const int* __restrict__ target,
                                   const int* __restrict__ path,
                                   int2* __restrict__ pairs,
                                   unsigned char* __restrict__ flags) {
    int p = blockIdx.x * blockDim.x + threadIdx.x;
    if (p >= NPAIRS) return;
    int s = p >> 10;          // BATCH == 1024
    int b = p & (BATCH - 1);
    int t = target[b];
    int n1 = path[t * HDEPTH + s];
    int n2 = path[t * HDEPTH + s + 1];
    pairs[p] = make_int2(n1, n2);
    flags[n1] = 1;            // benign write race: everyone writes 1
    flags[n2] = 1;
}

// ---------------------------------------------------------------------------
// Kernel B: pack L rows to 1 bit/class (bit = L==2). Only flagged rows.
// One block per row; 4 waves ballot 64 classes each per iteration.
// Row read once (40 KB) -> 1.25 KB of bits. ~334 MB HBM total vs 491 MB/sweep before.
// ---------------------------------------------------------------------------
__global__ void __launch_bounds__(256)
pack_bits_kernel(const int* __restrict__ L,
                 const unsigned char* __restrict__ flags,
                 unsigned int* __restrict__ packed) {
    const int row = blockIdx.x;
    if (!flags[row]) return;
    const int wave = threadIdx.x >> 6;
    const int lane = threadIdx.x & 63;
    const int* Lrow = L + (size_t)row * NCLASS;
    unsigned long long* prow = (unsigned long long*)(packed + (size_t)row * PACK_STRIDE);
#pragma unroll 2
    for (int g = wave; g < NGROUPS; g += 4) {
        int c = g * 64 + lane;
        int v = (c < NCLASS) ? Lrow[c] : 1;          // tail classes -> bit 0
        unsigned long long m = __ballot(v == 2);      // bit i = lane i = class g*64+i
        if (lane == 0) prow[g] = m;                   // words 2g,2g+1 (8B aligned)
    }
}

// ---------------------------------------------------------------------------
// Kernel C: main accumulation on bits.
//   r(L1,L2) = 1 + [a&~b] - 0.5*[~a&b]   (a=L1-1, b=L2-1)
// Thread owns one 32-class word column; block covers all 313 columns (320 thr).
// grid.x = 96 chunks of 64 pairs (single s per chunk -> weight hoisted, counts
// are exact integers). Epilogue stages per-class contributions in LDS so the
// global atomicAdds are class-contiguous (coalesced).
// ---------------------------------------------------------------------------
__global__ void __launch_bounds__(320)
hce_bits_kernel(const unsigned int* __restrict__ packed,
                const int2* __restrict__ pairs,
                float* __restrict__ out) {
    __shared__ float part[320 * 33];   // stride 33 floats: conflict-free write/read
    const int col = threadIdx.x;
    const bool active = (col < NCOLS);
    const int p0 = blockIdx.x * CHUNK;
    const int s = p0 >> 10;            // constant within chunk
    const float w = expf(-ALPHA * (float)(HDEPTH - 1 - s));
    // val(c) = w*(CHUNK + c2 - 0.5*cH); out += -val/BATCH
    //        = (-0.5*w/BATCH) * (2*CHUNK + 2*c2 - cH)
    const float mult = -0.5f * w / (float)BATCH;

    unsigned int c2[32], cH[32];
#pragma unroll
    for (int k = 0; k < 32; ++k) { c2[k] = 0u; cH[k] = 0u; }

#pragma unroll 4
    for (int p = p0; p < p0 + CHUNK; ++p) {
        int2 pr = pairs[p];            // uniform per block -> scalar/broadcast
        unsigned int wa = 0u, wb = 0u;
        if (active) {
            wa = packed[pr.x * PACK_STRIDE + col];   // 19.2 MB struct: LLC-resident
            wb = packed[pr.y * PACK_STRIDE + col];
        }
        unsigned int m2 = wa & ~wb;    // ratio 2   -> +1
        unsigned int mH = wb & ~wa;    // ratio 0.5 -> -0.5
#pragma unroll
        for (int k = 0; k < 32; ++k) {
            c2[k] += (m2 >> k) & 1u;   // v_bfe + v_add
            cH[k] += (mH >> k) & 1u;
        }
    }

#pragma unroll
    for (int k = 0; k < 32; ++k) {
        int t = 2 * CHUNK + 2 * (int)c2[k] - (int)cH[k];   // exact integer
        part[col * 33 + k] = mult * (float)t;
    }
    __syncthreads();
    // class-ordered, coalesced atomic flush (guards c < NCLASS: col 312 has
    // only 16 valid classes; cols >= 313 slots are never read)
    for (int c = col; c < NCLASS; c += 320) {
        atomicAdd(out + c, part[(c >> 5) * 33 + (c & 31)]);
    }
}

extern "C" void kernel_launch(void* const* d_in, const int* in_sizes, int n_in,
                              void* d_out, int out_size, void* d_ws, size_t ws_size,
                              hipStream_t stream) {
    // inputs: [0] logits (unused — cancels exactly), [1] target_classes,
    //         [2] L, [3] path_to_root
    const int* target = (const int*)d_in[1];
    const int* L      = (const int*)d_in[2];
    const int* path   = (const int*)d_in[3];
    float* out        = (float*)d_out;

    char* ws = (char*)d_ws;
    int2* pairs          = (int2*)ws;                       // 48 KiB
    unsigned char* flags = (unsigned char*)(ws + 49152);    // 15000 B
    unsigned int* packed = (unsigned int*)(ws + 65536);     // 15000*320*4 = 19.2 MB

    hipMemsetAsync(d_out, 0, NCLASS * sizeof(float), stream);
    hipMemsetAsync(flags, 0, NNODES, stream);

    build_pairs_kernel<<<(NPAIRS + 255) / 256, 256, 0, stream>>>(target, path, pairs, flags);
    pack_bits_kernel<<<NNODES, 256, 0, stream>>>(L, flags, packed);
    hce_bits_kernel<<<NCHUNKS, 320, 0, stream>>>(packed, pairs, out);
}

// Round 2
// 722.964 us; speedup vs baseline: 1.0997x; 1.0997x over previous
//
#include <hip/hip_runtime.h>

#define ALPHA 0.1f
#define HDEPTH 8
#define STEPS 6            // H - 2
#define NCLASS 10000
#define NNODES 15000
#define BATCH 1024
#define NPAIRS (BATCH * STEPS)   // 6144

#define PACK_B 1280        // bytes per packed row (1250 used; 10000 = 8*1250 exactly)
#define PACK_W 320         // u32 words per packed row
#define NCOLS 313          // u32 words carrying valid classes (word 312 = 16 classes)

#define CHUNK 16           // pairs per chunk (divides 1024 -> single s per chunk)
#define NCHUNKS (NPAIRS / CHUNK)  // 384
#define PCLASS 10240       // padded class stride of partial rows
#define COLTILE 128
#define NTILES 3           // ceil(313/128)

#define RSLICES 12
#define RCHUNK (NCHUNKS / RSLICES) // 32

// ---------------------------------------------------------------------------
// Kernel A: build (n1, n2) node pairs (s-major: p = s*1024 + b) and flag every
// referenced node so the pack kernel only touches ~5.4k of 15k rows.
// ---------------------------------------------------------------------------
__global__ void build_pairs_kernel(const int* __restrict__ target,
                                   const int* __restrict__ path,
                                   int2* __restrict__ pairs,
                                   unsigned char* __restrict__ flags) {
    int p = blockIdx.x * blockDim.x + threadIdx.x;
    if (p >= NPAIRS) return;
    int s = p >> 10;          // BATCH == 1024
    int b = p & (BATCH - 1);
    int t = target[b];
    int n1 = path[t * HDEPTH + s];
    int n2 = path[t * HDEPTH + s + 1];
    pairs[p] = make_int2(n1, n2);
    flags[n1] = 1;            // benign write race: everyone writes 1
    flags[n2] = 1;
}

// ---------------------------------------------------------------------------
// Kernel B: pack flagged L rows to 1 bit/class (bit = L==2, i.e. L>>1).
// Lane reads 8 consecutive classes (2x int4 = 32 B), packs one byte, stores it
// coalesced. 5 iterations cover 1280 bytes (1250 valid + zeroed pad).
// No ballot, no cross-lane, no compares -> short dependency chain, BW-bound.
// ---------------------------------------------------------------------------
__global__ void __launch_bounds__(256)
pack_bits_kernel(const int* __restrict__ L,
                 const unsigned char* __restrict__ flags,
                 unsigned char* __restrict__ packed) {
    const int row = blockIdx.x;
    if (!flags[row]) return;
    const int* Lrow = L + (size_t)row * NCLASS;      // 40000 B, 16B-aligned
    unsigned char* prow = packed + (size_t)row * PACK_B;
#pragma unroll
    for (int it = 0; it < 5; ++it) {
        int jb = it * 256 + threadIdx.x;             // byte index 0..1279
        unsigned int byte = 0u;
        if (jb < 1250) {
            const int4 a = *(const int4*)(Lrow + jb * 8);
            const int4 b = *(const int4*)(Lrow + jb * 8 + 4);
            byte  =  (unsigned)(a.x >> 1)
                  | ((unsigned)(a.y >> 1) << 1)
                  | ((unsigned)(a.z >> 1) << 2)
                  | ((unsigned)(a.w >> 1) << 3)
                  | ((unsigned)(b.x >> 1) << 4)
                  | ((unsigned)(b.y >> 1) << 5)
                  | ((unsigned)(b.z >> 1) << 6)
                  | ((unsigned)(b.w >> 1) << 7);
        }
        prow[jb] = (unsigned char)byte;              // pad bytes get 0
    }
}

// ---------------------------------------------------------------------------
// Kernel C: bit accumulation. grid = (384 chunks, 3 col tiles), 128 threads.
//   r(L1,L2) = 1 + [a&~b] - 0.5*[~a&b]
// 4 counters share one u32 via byte lanes: cp[k] accumulates classes
// col*32 + k + 8j in byte j (max count 16 < 256, exact). Writes weighted
// partial row per chunk -- no atomics.
// ---------------------------------------------------------------------------
__global__ void __launch_bounds__(128)
hce_bits_kernel(const unsigned int* __restrict__ packed,
                const int2* __restrict__ pairs,
                float* __restrict__ partial) {
    const int chunk = blockIdx.x;
    const int col = blockIdx.y * COLTILE + threadIdx.x;
    const bool active = (col < NCOLS);
    const int p0 = chunk * CHUNK;
    const int s = p0 >> 10;                          // constant within chunk
    const float w = __expf(-ALPHA * (float)(HDEPTH - 1 - s));
    // sum_p r = CHUNK + c2 - 0.5*cH ; out contribution = -(w/B)*sum
    //         = (-0.5*w/B) * (2*CHUNK + 2*c2 - cH)
    const float mult = -0.5f * w / (float)BATCH;

    unsigned int cp2[8], cpH[8];
#pragma unroll
    for (int k = 0; k < 8; ++k) { cp2[k] = 0u; cpH[k] = 0u; }

    const int2* pp = pairs + p0;                     // uniform -> s_load
#pragma unroll 4
    for (int i = 0; i < CHUNK; ++i) {
        int2 pr = pp[i];
        unsigned int wa = 0u, wb = 0u;
        if (active) {
            wa = packed[(size_t)pr.x * PACK_W + col];   // 256 B/wave, coalesced
            wb = packed[(size_t)pr.y * PACK_W + col];
        }
        unsigned int m2 = wa & ~wb;                  // ratio 2   -> +1
        unsigned int mH = wb & ~wa;                  // ratio 0.5 -> -0.5
#pragma unroll
        for (int k = 0; k < 8; ++k) {
            cp2[k] += (m2 >> k) & 0x01010101u;
            cpH[k] += (mH >> k) & 0x01010101u;
        }
    }

    if (active) {
        float v[32];
#pragma unroll
        for (int k = 0; k < 8; ++k) {
#pragma unroll
            for (int j = 0; j < 4; ++j) {
                int c2 = (int)((cp2[k] >> (8 * j)) & 0xFFu);
                int cH = (int)((cpH[k] >> (8 * j)) & 0xFFu);
                v[k + 8 * j] = mult * (float)(2 * CHUNK + 2 * c2 - cH);
            }
        }
        // 32 consecutive classes per thread -> 8 float4 stores (16B-aligned)
        float4* dst = (float4*)(partial + (size_t)chunk * PCLASS + col * 32);
#pragma unroll
        for (int q = 0; q < 8; ++q)
            dst[q] = make_float4(v[4*q], v[4*q+1], v[4*q+2], v[4*q+3]);
    }
}

// ---------------------------------------------------------------------------
// Kernel D: out[c] = sum over 384 chunks of partial[chunk][c].
// grid (10, 12): x covers 2500 float4 class-groups, y slices chunks by 32.
// 120k atomics total (out is memset to 0).
// ---------------------------------------------------------------------------
__global__ void __launch_bounds__(256)
reduce_kernel(const float4* __restrict__ partial, float* __restrict__ out) {
    int c4 = blockIdx.x * 256 + threadIdx.x;
    if (c4 >= NCLASS / 4) return;                    // 2500 float4 groups
    int k0 = blockIdx.y * RCHUNK;
    float4 s = make_float4(0.f, 0.f, 0.f, 0.f);
#pragma unroll
    for (int k = 0; k < RCHUNK; ++k) {
        float4 v = partial[(size_t)(k0 + k) * (PCLASS / 4) + c4];
        s.x += v.x; s.y += v.y; s.z += v.z; s.w += v.w;
    }
    int c = c4 * 4;
    atomicAdd(out + c + 0, s.x);
    atomicAdd(out + c + 1, s.y);
    atomicAdd(out + c + 2, s.z);
    atomicAdd(out + c + 3, s.w);
}

extern "C" void kernel_launch(void* const* d_in, const int* in_sizes, int n_in,
                              void* d_out, int out_size, void* d_ws, size_t ws_size,
                              hipStream_t stream) {
    // inputs: [0] logits (unused -- cancels exactly), [1] target_classes,
    //         [2] L, [3] path_to_root
    const int* target = (const int*)d_in[1];
    const int* L      = (const int*)d_in[2];
    const int* path   = (const int*)d_in[3];
    float* out        = (float*)d_out;

    char* ws = (char*)d_ws;
    int2* pairs           = (int2*)ws;                        // 48 KiB
    unsigned char* flags  = (unsigned char*)(ws + 49152);     // 15000 B
    unsigned char* packed = (unsigned char*)(ws + 65536);     // 15000*1280 = 19.2 MB
    float* partial        = (float*)(ws + 19267584);          // 384*10240*4 = 15.7 MB

    hipMemsetAsync(d_out, 0, NCLASS * sizeof(float), stream);
    hipMemsetAsync(flags, 0, NNODES, stream);

    build_pairs_kernel<<<(NPAIRS + 255) / 256, 256, 0, stream>>>(target, path, pairs, flags);
    pack_bits_kernel<<<NNODES, 256, 0, stream>>>(L, flags, packed);

    dim3 gridC(NCHUNKS, NTILES);
    hce_bits_kernel<<<gridC, COLTILE, 0, stream>>>((const unsigned int*)packed, pairs, partial);

    dim3 gridR((NCLASS / 4 + 255) / 256, RSLICES);
    reduce_kernel<<<gridR, 256, 0, stream>>>((const float4*)partial, out);
}

// Round 4
// 715.920 us; speedup vs baseline: 1.1106x; 1.0098x over previous
//
#include <hip/hip_runtime.h>

#define ALPHA 0.1f
#define HDEPTH 8
#define STEPS 6            // H - 2
#define NCLASS 10000
#define NNODES 15000
#define BATCH 1024
#define NPAIRS (BATCH * STEPS)   // 6144

#define PACK_B 1280        // bytes per packed row (1250 used; 10000 = 8*1250 exactly)
#define PACK_W 320         // u32 words per packed row
#define NCOLS 313          // u32 words carrying valid classes (word 312 = 16 classes)

#define CHUNK 16           // pairs per chunk (divides 1024 -> single s per chunk)
#define NCHUNKS (NPAIRS / CHUNK)  // 384
#define PCLASS 10240       // padded class stride of partial rows
#define COLTILE 128
#define NTILES 3           // ceil(313/128)

#define RSLICES 12
#define RCHUNK (NCHUNKS / RSLICES) // 32

typedef int   v4i __attribute__((ext_vector_type(4)));
typedef float v4f __attribute__((ext_vector_type(4)));

// ---------------------------------------------------------------------------
// Kernel A: build (n1, n2) node pairs (s-major: p = s*1024 + b) and flag every
// referenced node so the pack kernel only touches ~5.5k of 15k rows.
// ---------------------------------------------------------------------------
__global__ void build_pairs_kernel(const int* __restrict__ target,
                                   const int* __restrict__ path,
                                   int2* __restrict__ pairs,
                                   unsigned char* __restrict__ flags) {
    int p = blockIdx.x * blockDim.x + threadIdx.x;
    if (p >= NPAIRS) return;
    int s = p >> 10;          // BATCH == 1024
    int b = p & (BATCH - 1);
    int t = target[b];
    int n1 = path[t * HDEPTH + s];
    int n2 = path[t * HDEPTH + s + 1];
    pairs[p] = make_int2(n1, n2);
    flags[n1] = 1;            // benign write race: everyone writes 1
    flags[n2] = 1;
}

// ---------------------------------------------------------------------------
// Kernel B: pack flagged L rows to 1 bit/class (bit = L==2, i.e. L>>1).
// Lane reads 8 consecutive classes (2x nontemporal dwordx4 = 32 B — L is
// read-once, keep it out of L2/LLC so `packed` stays resident for kernel C),
// packs one byte, stores it coalesced. Iters 0..3 are branch-free (jb<=1023);
// only iter 4 needs the 1250-tail guard.
// ---------------------------------------------------------------------------
__global__ void __launch_bounds__(256)
pack_bits_kernel(const int* __restrict__ L,
                 const unsigned char* __restrict__ flags,
                 unsigned char* __restrict__ packed) {
    const int row = blockIdx.x;
    if (!flags[row]) return;
    const int* Lrow = L + (size_t)row * NCLASS;      // 40000 B, 16B-aligned
    unsigned char* prow = packed + (size_t)row * PACK_B;
#pragma unroll
    for (int it = 0; it < 5; ++it) {
        int jb = it * 256 + threadIdx.x;             // byte index 0..1279
        unsigned int byte = 0u;
        if (it < 4 || jb < 1250) {
            const v4i a = __builtin_nontemporal_load((const v4i*)(Lrow + jb * 8));
            const v4i b = __builtin_nontemporal_load((const v4i*)(Lrow + jb * 8) + 1);
            byte  =  (unsigned)(a.x >> 1)
                  | ((unsigned)(a.y >> 1) << 1)
                  | ((unsigned)(a.z >> 1) << 2)
                  | ((unsigned)(a.w >> 1) << 3)
                  | ((unsigned)(b.x >> 1) << 4)
                  | ((unsigned)(b.y >> 1) << 5)
                  | ((unsigned)(b.z >> 1) << 6)
                  | ((unsigned)(b.w >> 1) << 7);
        }
        prow[jb] = (unsigned char)byte;              // pad bytes get 0
    }
}

// ---------------------------------------------------------------------------
// Kernel C: bit accumulation. grid = (384 chunks, 3 col tiles), 128 threads.
//   r(L1,L2) = 1 + [a&~b] - 0.5*[~a&b]
// 4 counters share one u32 via byte lanes: cp[k] accumulates classes
// col*32 + k + 8j in byte j (max count 16 < 256, exact). Writes weighted
// partial row per chunk -- no atomics.
// ---------------------------------------------------------------------------
__global__ void __launch_bounds__(128)
hce_bits_kernel(const unsigned int* __restrict__ packed,
                const int2* __restrict__ pairs,
                float* __restrict__ partial) {
    const int chunk = blockIdx.x;
    const int col = blockIdx.y * COLTILE + threadIdx.x;
    const bool active = (col < NCOLS);
    const int p0 = chunk * CHUNK;
    const int s = p0 >> 10;                          // constant within chunk
    const float w = __expf(-ALPHA * (float)(HDEPTH - 1 - s));
    // sum_p r = CHUNK + c2 - 0.5*cH ; out contribution = -(w/B)*sum
    //         = (-0.5*w/B) * (2*CHUNK + 2*c2 - cH)
    const float mult = -0.5f * w / (float)BATCH;

    unsigned int cp2[8], cpH[8];
#pragma unroll
    for (int k = 0; k < 8; ++k) { cp2[k] = 0u; cpH[k] = 0u; }

    const int2* pp = pairs + p0;                     // uniform -> scalar/broadcast
#pragma unroll 4
    for (int i = 0; i < CHUNK; ++i) {
        int2 pr = pp[i];
        unsigned int wa = 0u, wb = 0u;
        if (active) {
            wa = packed[(size_t)pr.x * PACK_W + col];   // 512 B/block, coalesced
            wb = packed[(size_t)pr.y * PACK_W + col];
        }
        unsigned int m2 = wa & ~wb;                  // ratio 2   -> +1
        unsigned int mH = wb & ~wa;                  // ratio 0.5 -> -0.5
#pragma unroll
        for (int k = 0; k < 8; ++k) {
            cp2[k] += (m2 >> k) & 0x01010101u;
            cpH[k] += (mH >> k) & 0x01010101u;
        }
    }

    if (active) {
        float v[32];
#pragma unroll
        for (int k = 0; k < 8; ++k) {
#pragma unroll
            for (int j = 0; j < 4; ++j) {
                int c2 = (int)((cp2[k] >> (8 * j)) & 0xFFu);
                int cH = (int)((cpH[k] >> (8 * j)) & 0xFFu);
                v[k + 8 * j] = mult * (float)(2 * CHUNK + 2 * c2 - cH);
            }
        }
        // 32 consecutive classes per thread -> 8 float4 stores (16B-aligned)
        float4* dst = (float4*)(partial + (size_t)chunk * PCLASS + col * 32);
#pragma unroll
        for (int q = 0; q < 8; ++q)
            dst[q] = make_float4(v[4*q], v[4*q+1], v[4*q+2], v[4*q+3]);
    }
}

// ---------------------------------------------------------------------------
// Kernel D: out[c] = sum over 384 chunks of partial[chunk][c].
// grid (10, 12): x covers 2500 float4 class-groups, y slices chunks by 32.
// partial is read-once -> nontemporal. 120k atomics total (out memset to 0).
// ---------------------------------------------------------------------------
__global__ void __launch_bounds__(256)
reduce_kernel(const float* __restrict__ partial, float* __restrict__ out) {
    int c4 = blockIdx.x * 256 + threadIdx.x;
    if (c4 >= NCLASS / 4) return;                    // 2500 float4 groups
    int k0 = blockIdx.y * RCHUNK;
    float sx = 0.f, sy = 0.f, sz = 0.f, sw = 0.f;
#pragma unroll
    for (int k = 0; k < RCHUNK; ++k) {
        const v4f v = __builtin_nontemporal_load(
            (const v4f*)(partial + (size_t)(k0 + k) * PCLASS) + c4);
        sx += v.x; sy += v.y; sz += v.z; sw += v.w;
    }
    int c = c4 * 4;
    atomicAdd(out + c + 0, sx);
    atomicAdd(out + c + 1, sy);
    atomicAdd(out + c + 2, sz);
    atomicAdd(out + c + 3, sw);
}

extern "C" void kernel_launch(void* const* d_in, const int* in_sizes, int n_in,
                              void* d_out, int out_size, void* d_ws, size_t ws_size,
                              hipStream_t stream) {
    // inputs: [0] logits (unused -- cancels exactly), [1] target_classes,
    //         [2] L, [3] path_to_root
    const int* target = (const int*)d_in[1];
    const int* L      = (const int*)d_in[2];
    const int* path   = (const int*)d_in[3];
    float* out        = (float*)d_out;

    char* ws = (char*)d_ws;
    int2* pairs           = (int2*)ws;                        // 48 KiB
    unsigned char* flags  = (unsigned char*)(ws + 49152);     // 15000 B
    unsigned char* packed = (unsigned char*)(ws + 65536);     // 15000*1280 = 19.2 MB
    float* partial        = (float*)(ws + 19267584);          // 384*10240*4 = 15.7 MB

    hipMemsetAsync(d_out, 0, NCLASS * sizeof(float), stream);
    hipMemsetAsync(flags, 0, NNODES, stream);

    build_pairs_kernel<<<(NPAIRS + 255) / 256, 256, 0, stream>>>(target, path, pairs, flags);
    pack_bits_kernel<<<NNODES, 256, 0, stream>>>(L, flags, packed);

    dim3 gridC(NCHUNKS, NTILES);
    hce_bits_kernel<<<gridC, COLTILE, 0, stream>>>((const unsigned int*)packed, pairs, partial);

    dim3 gridR((NCLASS / 4 + 255) / 256, RSLICES);
    reduce_kernel<<<gridR, 256, 0, stream>>>(partial, out);
}